// Round 2
// baseline (852.093 us; speedup 1.0000x reference)
//
#include <hip/hip_runtime.h>
#include <stdint.h>
#include <stddef.h>

// Problem constants (fixed by the reference)
#define M_ROWS 32768      // B*N = 16*2048
#define N_CODES 8192
#define K_DIM 512
#define BM 256
#define BN 256
#define BK 64
#define KTILES (K_DIM / BK)     // 8 K-tiles, processed 2 per pipeline iteration
#define CAND_CAP (3u*1024u*1024u)
#define LCAP 1024u              // per-block LDS candidate slab
#define TAU2 2.0f               // 2*tau admission margin for bf16 approx distances (>10 sigma)

// Output layout (floats): z_q [0,16777216), codes [16777216,16809984), loss, perp
#define OFF_CODES 16777216
#define OFF_LOSS  (16777216 + 32768)
#define OFF_PERP  (16777216 + 32768 + 1)

using short8  = __attribute__((ext_vector_type(8))) short;
using ushort8 = __attribute__((ext_vector_type(8))) unsigned short;
using f32x4   = __attribute__((ext_vector_type(4))) float;

typedef unsigned short u16;
typedef unsigned int   u32;
typedef unsigned long long u64;

// ---- orderable-uint encoding of float (monotone: uint min == float min) ----
__device__ __forceinline__ u32 ford(float f) {
    u32 u = __float_as_uint(f);
    return (u & 0x80000000u) ? ~u : (u | 0x80000000u);
}
__device__ __forceinline__ float fordinv(u32 u) {
    u32 v = (u & 0x80000000u) ? (u & 0x7FFFFFFFu) : ~u;
    return __uint_as_float(v);
}
// fp32 -> bf16 (RNE)
__device__ __forceinline__ u16 f2bf(float f) {
    u32 u = __float_as_uint(f);
    u = u + 0x7FFFu + ((u >> 16) & 1u);
    return (u16)(u >> 16);
}

// async global->LDS, 16B per lane; LDS dest = wave-uniform base + lane*16
__device__ __forceinline__ void ldg_to_lds16(const u16* g, u16* l) {
    __builtin_amdgcn_global_load_lds((__attribute__((address_space(1))) void*)(g),
                                     (__attribute__((address_space(3))) void*)(l),
                                     16, 0, 0);
}

// ---------------- init scratch state ----------------
__global__ void k_init(u32* rowMin, u64* rowBest, u32* counts, u32* candCnt) {
    int i = blockIdx.x * blockDim.x + threadIdx.x;
    if (i < M_ROWS) { rowMin[i] = 0xFFFFFFFFu; rowBest[i] = ~0ull; }
    if (i < N_CODES) counts[i] = 0u;
    if (i == 0) *candCnt = 0u;
}

// ------------- fp32 -> bf16 convert + row squared norms -------------
__global__ void k_convert(const float* __restrict__ src, u16* __restrict__ dst,
                          float* __restrict__ nrm2, int nrows) {
    int row  = blockIdx.x * 4 + (threadIdx.x >> 6);
    int lane = threadIdx.x & 63;
    if (row >= nrows) return;
    const float* p = src + (size_t)row * K_DIM + lane * 8;
    float4 a = *(const float4*)p;
    float4 b = *(const float4*)(p + 4);
    ushort8 v;
    v[0]=f2bf(a.x); v[1]=f2bf(a.y); v[2]=f2bf(a.z); v[3]=f2bf(a.w);
    v[4]=f2bf(b.x); v[5]=f2bf(b.y); v[6]=f2bf(b.z); v[7]=f2bf(b.w);
    *(ushort8*)(dst + (size_t)row * K_DIM + lane * 8) = v;
    float ss = a.x*a.x + a.y*a.y + a.z*a.z + a.w*a.w
             + b.x*b.x + b.y*b.y + b.z*b.z + b.w*b.w;
    #pragma unroll
    for (int s = 32; s; s >>= 1) ss += __shfl_xor(ss, s);
    if (lane == 0) nrm2[row] = ss;
}

// ---------------- main bf16 GEMM + fused min/candidate epilogue ----------------
// 256x256 tile, BK=64, 8 waves (2M x 4N), 8-phase pipeline with counted vmcnt.
//
// LDS A/B slabs are K-HALF granular (32 cols = 64B/row), stored as 16B blocks:
//   block(row R, q) at slot (R>>3)*32 + q*8 + (R&7)   (q = 16B block within 64B)
// Staging block index b (0..1023 per half-slab; 2 issues x 512 threads) lands at
// LDS block b, and slot(R(b), q(b)) == b identically -> staging dest stays
// lane-linear (global_load_lds requirement) while ds_read_b128 frag reads are
// conflict-free (8 consecutive lanes cover 128 contiguous LDS bytes).
//
// Phase map (iter i computes tiles t=2i from buf0, u=2i+1 from buf1; stages
// one half-slab/phase; WAR-safe because each target region's readers finished
// before the previous phase's closing barrier):
//   ph1: rd B0h0,A0h0 mp0-3 | stage buf1.A.h1(u)      ph5: rd B1h0,A1h0 | stage buf0.A.h1(t+2)
//   ph2: rd A0h0 mp4-7      | stage buf1.B.h1(u)      ph6: rd A1h0 mp4-7| stage buf0.B.h1(t+2)
//   ph3: rd B0h1,A0h1 mp0-3 | stage buf0.A.h0(t+2)    ph7: rd B1h1,A1h1 | stage buf1.A.h0(t+3)
//   ph4: rd A0h1 mp4-7      | stage buf0.B.h0(t+2)    ph8: rd A1h1 mp4-7| stage buf1.B.h0(t+3)
// vmcnt(4) ONLY at ph4/ph8 (retires the 8 oldest loads = everything read in
// the next 1-4 phases; leaves newest 2 half-slabs in flight). Never drained
// to 0 inside the loop (T4). K-slices accumulate in ascending order ->
// numerics identical to the verified 128-tile kernel.
__global__ __launch_bounds__(512, 2)
void k_gemm(const u16* __restrict__ zb, const u16* __restrict__ eb,
            const float* __restrict__ en2, u32* __restrict__ rowMin,
            u32* __restrict__ candCnt, u64* __restrict__ cand) {
    // [buf(2)][mat A/B][khalf(2)][8192 u16] = 128 KiB
    __shared__ __align__(16) u16 lds[65536];
    __shared__ float en2s[BN];
    __shared__ u32 threshL[BM];
    __shared__ u64 candBuf[LCAP];
    __shared__ u32 ldsCnt, ldsBase;

    const int tid  = threadIdx.x;
    const int lane = tid & 63;
    const int wave = tid >> 6;          // 0..7
    const int wm   = wave >> 2;         // 0..1: row half (128 rows per wave)
    const int wn   = (wave & 3) * 64;   // col quadrant base (64 cols per wave)
    const int rowTile = blockIdx.x * BM;
    const int nTile   = blockIdx.y * BN;

    if (tid < BN) en2s[tid] = en2[nTile + tid];
    if (tid < BM) threshL[tid] = 0xFFFFFFFFu;
    if (tid == 0) ldsCnt = 0u;

    // --- staging addresses: 16B block b=(wave*2+j)*64+lane; G=b>>5,q=(b>>3)&3,r=b&7
    //     holds global (row G*8+r, u16 cols q*8..+8 of the 32-col half).
    const u16* zbp = zb + (size_t)rowTile * K_DIM;
    const u16* ebp = eb + (size_t)nTile * K_DIM;
    int b0 = (wave*2 + 0)*64 + lane;
    int b1 = (wave*2 + 1)*64 + lane;
    const size_t gOff0 = (size_t)((b0 >> 5)*8 + (b0 & 7)) * K_DIM + ((b0 >> 3) & 3)*8;
    const size_t gOff1 = (size_t)((b1 >> 5)*8 + (b1 & 7)) * K_DIM + ((b1 >> 3) & 3)*8;
    const int lOff0 = (wave*2 + 0) * 512;
    const int lOff1 = (wave*2 + 1) * 512;

    // --- fragment read offsets: slot(R,q)*8 = (R>>3)*256 + q*64 + (R&7)*8
    const int laneF = ((lane >> 3) & 1)*256 + (lane >> 4)*64 + (lane & 7)*8;
    const int aBase = wm*4096 + laneF;             // + mp*512
    const int bBase = (wave & 3)*2048 + laneF;     // + nr*512

#define STAGE(buf, matB, h, tileIdx) do {                                     \
    int t_ = (tileIdx); t_ = (t_ < KTILES) ? t_ : 0;  /* clamp keeps vmcnt cadence uniform */ \
    int ko_ = t_ * BK + (h) * 32;                                             \
    const u16* g_ = (matB) ? ebp : zbp;                                       \
    u16* l_ = lds + (buf)*32768 + (matB)*16384 + (h)*8192;                    \
    ldg_to_lds16(g_ + gOff0 + ko_, l_ + lOff0);                               \
    ldg_to_lds16(g_ + gOff1 + ko_, l_ + lOff1);                               \
} while (0)

#define RD_A(buf, h, mpB) do {                                                \
    const u16* p_ = lds + (buf)*32768 + (h)*8192 + aBase + (mpB)*512;         \
    af[0] = *(const short8*)(p_);                                             \
    af[1] = *(const short8*)(p_ + 512);                                       \
    af[2] = *(const short8*)(p_ + 1024);                                      \
    af[3] = *(const short8*)(p_ + 1536);                                      \
} while (0)

#define RD_B(buf, h) do {                                                     \
    const u16* p_ = lds + (buf)*32768 + 16384 + (h)*8192 + bBase;             \
    bf[0] = *(const short8*)(p_);                                             \
    bf[1] = *(const short8*)(p_ + 512);                                       \
    bf[2] = *(const short8*)(p_ + 1024);                                      \
    bf[3] = *(const short8*)(p_ + 1536);                                      \
} while (0)

#define BARF() do { asm volatile("" ::: "memory");                            \
    __builtin_amdgcn_s_barrier(); asm volatile("" ::: "memory"); } while (0)
#define VMW4() asm volatile("s_waitcnt vmcnt(4)" ::: "memory")

#define MFMA_Q(mpB) do {                                                      \
    __builtin_amdgcn_s_setprio(1);                                            \
    _Pragma("unroll") for (int m_ = 0; m_ < 4; m_++)                          \
      _Pragma("unroll") for (int n_ = 0; n_ < 4; n_++)                        \
        acc[(mpB)+m_][n_] = __builtin_amdgcn_mfma_f32_16x16x32_bf16(          \
            af[m_], bf[n_], acc[(mpB)+m_][n_], 0, 0, 0);                      \
    __builtin_amdgcn_s_setprio(0);                                            \
} while (0)

    f32x4 acc[8][4] = {};
    short8 af[4], bf[4];

    // prologue: tile0 fully + tile1 h0; vmcnt(4) -> tile0's 4 half-slabs landed
    STAGE(0,0,0,0); STAGE(0,1,0,0); STAGE(0,0,1,0); STAGE(0,1,1,0);
    STAGE(1,0,0,1); STAGE(1,1,0,1);
    VMW4();
    BARF();

    for (int i = 0; i < KTILES/2; i++) {
        const int t = 2*i, u = t + 1;
        RD_B(0,0); RD_A(0,0,0); STAGE(1,0,1,u);          // ph1
        BARF(); MFMA_Q(0); BARF();
        RD_A(0,0,4); STAGE(1,1,1,u);                     // ph2
        BARF(); MFMA_Q(4); BARF();
        RD_B(0,1); RD_A(0,1,0); STAGE(0,0,0,t+2);        // ph3
        BARF(); MFMA_Q(0); BARF();
        RD_A(0,1,4); STAGE(0,1,0,t+2); VMW4();           // ph4
        BARF(); MFMA_Q(4); BARF();
        RD_B(1,0); RD_A(1,0,0); STAGE(0,0,1,t+2);        // ph5
        BARF(); MFMA_Q(0); BARF();
        RD_A(1,0,4); STAGE(0,1,1,t+2);                   // ph6
        BARF(); MFMA_Q(4); BARF();
        RD_B(1,1); RD_A(1,1,0); STAGE(1,0,0,t+3);        // ph7
        BARF(); MFMA_Q(0); BARF();
        RD_A(1,1,4); STAGE(1,1,0,t+3); VMW4();           // ph8
        BARF(); MFMA_Q(4); BARF();
    }

    // ---- epilogue: s = en2 - 2*C ; per-row tile min ; candidate capture ----
    // C/D layout (16x16x32): col = lane&15, row = (lane>>4)*4 + reg
    float e2v[4];
    #pragma unroll
    for (int n = 0; n < 4; n++) e2v[n] = en2s[wn + n*16 + (lane & 15)];
    #pragma unroll
    for (int m = 0; m < 8; m++)
        #pragma unroll
        for (int n = 0; n < 4; n++)
            #pragma unroll
            for (int r = 0; r < 4; r++)
                acc[m][n][r] = e2v[n] - 2.0f * acc[m][n][r];

    float rm[8][4];
    #pragma unroll
    for (int m = 0; m < 8; m++)
        #pragma unroll
        for (int r = 0; r < 4; r++)
            rm[m][r] = fminf(fminf(acc[m][0][r], acc[m][1][r]),
                             fminf(acc[m][2][r], acc[m][3][r]));
    #pragma unroll
    for (int d = 1; d < 16; d <<= 1)
        #pragma unroll
        for (int m = 0; m < 8; m++)
            #pragma unroll
            for (int r = 0; r < 4; r++)
                rm[m][r] = fminf(rm[m][r], __shfl_xor(rm[m][r], d));

    const int q4 = lane >> 4;
    if ((lane & 15) == 0) {
        #pragma unroll
        for (int m = 0; m < 8; m++)
            #pragma unroll
            for (int r = 0; r < 4; r++) {
                int lrow = wm*128 + m*16 + q4*4 + r;
                u32 o = ford(rm[m][r]);
                atomicMin(&threshL[lrow], o);
                u32 old = atomicMin(&rowMin[rowTile + lrow], o);  // tighten via earlier tiles
                atomicMin(&threshL[lrow], old);
            }
    }
    __syncthreads();   // full drain here is fine (loop done); also syncs threshL

    #pragma unroll
    for (int m = 0; m < 8; m++) {
        #pragma unroll
        for (int r = 0; r < 4; r++) {
            int lrow = wm*128 + m*16 + q4*4 + r;
            float th = fordinv(threshL[lrow]) + TAU2;
            #pragma unroll
            for (int n = 0; n < 4; n++) {
                float sv = acc[m][n][r];
                if (sv <= th) {
                    u32 code = (u32)(nTile + wn + n*16 + (lane & 15));
                    u64 pk = ((u64)ford(sv) << 32) |
                             (u64)(((u32)(rowTile + lrow) << 13) | code);
                    u32 idx = atomicAdd(&ldsCnt, 1u);       // LDS atomic: cheap
                    if (idx < LCAP) candBuf[idx] = pk;
                    else { u32 g = atomicAdd(candCnt, 1u);  // rare overflow path
                           if (g < CAND_CAP) cand[g] = pk; }
                }
            }
        }
    }
    __syncthreads();
    if (tid == 0) {
        u32 n = ldsCnt < LCAP ? ldsCnt : LCAP;
        ldsBase = atomicAdd(candCnt, n);                    // ONE global atomic per block
    }
    __syncthreads();
    u32 nn = ldsCnt < LCAP ? ldsCnt : LCAP;
    for (u32 k2 = tid; k2 < nn; k2 += 512) {
        u32 g = ldsBase + k2;
        if (g < CAND_CAP) cand[g] = candBuf[k2];
    }
#undef STAGE
#undef RD_A
#undef RD_B
#undef BARF
#undef VMW4
#undef MFMA_Q
}

// ---------------- fp32 exact refine of pruned candidates ----------------
__global__ void k_refine(const float* __restrict__ z, const float* __restrict__ emb,
                         const float* __restrict__ en2, const u32* __restrict__ candCnt,
                         const u64* __restrict__ cand, const u32* __restrict__ rowMin,
                         u64* __restrict__ rowBest) {
    u32 cnt = *candCnt; if (cnt > CAND_CAP) cnt = CAND_CAP;
    int gt = blockIdx.x * blockDim.x + threadIdx.x;
    u32 wid = (u32)(gt >> 6);
    int lane = gt & 63;
    u32 nw = (u32)((gridDim.x * blockDim.x) >> 6);
    for (u32 ci = wid; ci < cnt; ci += nw) {
        u64 pk = cand[ci];
        u32 rc = (u32)pk;
        u32 row = rc >> 13, code = rc & (N_CODES - 1);
        float ad = fordinv((u32)(pk >> 32));
        float gm = fordinv(rowMin[row]);
        if (ad > gm + TAU2) continue;   // pruned: can't be the true argmin
        const float4* zp = (const float4*)(z + (size_t)row * K_DIM) + lane * 2;
        const float4* ep = (const float4*)(emb + (size_t)code * K_DIM) + lane * 2;
        float4 a0 = zp[0], a1 = zp[1], b0 = ep[0], b1 = ep[1];
        float d = a0.x*b0.x + a0.y*b0.y + a0.z*b0.z + a0.w*b0.w
                + a1.x*b1.x + a1.y*b1.y + a1.z*b1.z + a1.w*b1.w;
        #pragma unroll
        for (int s = 32; s; s >>= 1) d += __shfl_xor(d, s);
        if (lane == 0) {
            float sv = en2[code] - 2.0f * d;
            u64 bk = ((u64)ford(sv) << 32) | (u64)code;
            atomicMin(rowBest + row, bk);
        }
    }
}

// ---------------- outputs: z_q gather, codes, counts ----------------
__global__ void k_output(const u64* __restrict__ rowBest, const float* __restrict__ emb,
                         float* __restrict__ out, u32* __restrict__ counts) {
    int row = blockIdx.x;
    u64 pk = rowBest[row];
    u32 code = (u32)(pk & 0xFFFFFFFFull);
    int t = threadIdx.x;  // 128 threads, 4 floats each
    float4 v = ((const float4*)(emb + (size_t)code * K_DIM))[t];
    ((float4*)(out + (size_t)row * K_DIM))[t] = v;
    if (t == 0) {
        out[OFF_CODES + row] = (float)code;
        atomicAdd(&counts[code], 1u);
    }
}

// ---------------- loss + perplexity ----------------
__global__ void k_final(const u64* __restrict__ rowBest, const float* __restrict__ zn2,
                        const u32* __restrict__ counts, float* __restrict__ out) {
    __shared__ float red[256];
    int t = threadIdx.x;
    float s1 = 0.f;
    for (int r = t; r < M_ROWS; r += 256)
        s1 += zn2[r] + fordinv((u32)(rowBest[r] >> 32));
    red[t] = s1; __syncthreads();
    for (int w = 128; w; w >>= 1) { if (t < w) red[t] += red[t + w]; __syncthreads(); }
    float lossSum = red[0];
    __syncthreads();
    float s2 = 0.f;
    for (int c = t; c < N_CODES; c += 256) {
        float p = (float)counts[c] * (1.0f / (float)M_ROWS);
        s2 += p * logf(p + 1e-10f);
    }
    red[t] = s2; __syncthreads();
    for (int w = 128; w; w >>= 1) { if (t < w) red[t] += red[t + w]; __syncthreads(); }
    if (t == 0) {
        out[OFF_LOSS] = 0.25f * lossSum / ((float)M_ROWS * (float)K_DIM);
        out[OFF_PERP] = expf(-red[0]);
    }
}

// ---------------- workspace layout (bytes) ----------------
#define WS_ZB      ((size_t)0)                       // 32768*512*2  = 33554432
#define WS_EB      ((size_t)33554432)                // 8192*512*2   = 8388608
#define WS_EN2     ((size_t)41943040)                // 8192*4
#define WS_ZN2     ((size_t)41975808)                // 32768*4
#define WS_ROWMIN  ((size_t)42106880)                // 32768*4
#define WS_ROWBEST ((size_t)42237952)                // 32768*8
#define WS_COUNTS  ((size_t)42500096)                // 8192*4
#define WS_CANDCNT ((size_t)42532864)                // 256
#define WS_CAND    ((size_t)42533120)                // 3M*8 = 25165824 -> total ~67.7MB

extern "C" void kernel_launch(void* const* d_in, const int* in_sizes, int n_in,
                              void* d_out, int out_size, void* d_ws, size_t ws_size,
                              hipStream_t stream) {
    const float* z   = (const float*)d_in[0];
    const float* emb = (const float*)d_in[1];
    float* out = (float*)d_out;
    char* ws = (char*)d_ws;

    u16*  zb      = (u16*)(ws + WS_ZB);
    u16*  eb      = (u16*)(ws + WS_EB);
    float* en2    = (float*)(ws + WS_EN2);
    float* zn2    = (float*)(ws + WS_ZN2);
    u32*  rowMin  = (u32*)(ws + WS_ROWMIN);
    u64*  rowBest = (u64*)(ws + WS_ROWBEST);
    u32*  counts  = (u32*)(ws + WS_COUNTS);
    u32*  candCnt = (u32*)(ws + WS_CANDCNT);
    u64*  cand    = (u64*)(ws + WS_CAND);

    k_init<<<dim3(M_ROWS / 256), dim3(256), 0, stream>>>(rowMin, rowBest, counts, candCnt);
    k_convert<<<dim3(M_ROWS / 4), dim3(256), 0, stream>>>(z, zb, zn2, M_ROWS);
    k_convert<<<dim3(N_CODES / 4), dim3(256), 0, stream>>>(emb, eb, en2, N_CODES);
    k_gemm<<<dim3(M_ROWS / BM, N_CODES / BN), dim3(512), 0, stream>>>(zb, eb, en2, rowMin, candCnt, cand);
    k_refine<<<dim3(1024), dim3(256), 0, stream>>>(z, emb, en2, candCnt, cand, rowMin, rowBest);
    k_output<<<dim3(M_ROWS), dim3(128), 0, stream>>>(rowBest, emb, out, counts);
    k_final<<<dim3(1), dim3(256), 0, stream>>>(rowBest, zn2, counts, out);
}

// Round 4
// 795.030 us; speedup vs baseline: 1.0718x; 1.0718x over previous
//
#include <hip/hip_runtime.h>
#include <stdint.h>
#include <stddef.h>

// Problem constants (fixed by the reference)
#define M_ROWS 32768      // B*N = 16*2048
#define N_CODES 8192
#define K_DIM 512
#define BM 256
#define BN 256
#define BK 64
#define KTILES (K_DIM / BK)     // 8 K-tiles, 2 per pipeline iteration
#define CAND_CAP (3u*1024u*1024u)
#define LCAP 1024u              // per-block LDS candidate slab
#define TAU2 2.0f               // 2*tau admission margin for bf16 approx distances (>10 sigma)

// Output layout (floats): z_q [0,16777216), codes [16777216,16809984), loss, perp
#define OFF_CODES 16777216
#define OFF_LOSS  (16777216 + 32768)
#define OFF_PERP  (16777216 + 32768 + 1)

using short8  = __attribute__((ext_vector_type(8))) short;
using ushort8 = __attribute__((ext_vector_type(8))) unsigned short;
using f32x4   = __attribute__((ext_vector_type(4))) float;

typedef unsigned short u16;
typedef unsigned int   u32;
typedef unsigned long long u64;

// ---- orderable-uint encoding of float (monotone: uint min == float min) ----
__device__ __forceinline__ u32 ford(float f) {
    u32 u = __float_as_uint(f);
    return (u & 0x80000000u) ? ~u : (u | 0x80000000u);
}
__device__ __forceinline__ float fordinv(u32 u) {
    u32 v = (u & 0x80000000u) ? (u & 0x7FFFFFFFu) : ~u;
    return __uint_as_float(v);
}
// fp32 -> bf16 (RNE)
__device__ __forceinline__ u16 f2bf(float f) {
    u32 u = __float_as_uint(f);
    u = u + 0x7FFFu + ((u >> 16) & 1u);
    return (u16)(u >> 16);
}

// async global->LDS, 16B per lane; LDS dest = wave-uniform base + lane*16
__device__ __forceinline__ void ldg_to_lds16(const u16* g, u16* l) {
    __builtin_amdgcn_global_load_lds((__attribute__((address_space(1))) void*)(g),
                                     (__attribute__((address_space(3))) void*)(l),
                                     16, 0, 0);
}
// generic (__shared__) pointer -> 32-bit LDS byte address for asm ds ops
__device__ __forceinline__ u32 lds_addr(const void* p) {
    return (u32)(uintptr_t)(__attribute__((address_space(3))) const void*)p;
}

// ---------------- init scratch state ----------------
__global__ void k_init(u32* rowMin, u64* rowBest, u32* counts, u32* candCnt) {
    int i = blockIdx.x * blockDim.x + threadIdx.x;
    if (i < M_ROWS) { rowMin[i] = 0xFFFFFFFFu; rowBest[i] = ~0ull; }
    if (i < N_CODES) counts[i] = 0u;
    if (i == 0) *candCnt = 0u;
}

// ------------- fp32 -> bf16 convert + row squared norms -------------
__global__ void k_convert(const float* __restrict__ src, u16* __restrict__ dst,
                          float* __restrict__ nrm2, int nrows) {
    int row  = blockIdx.x * 4 + (threadIdx.x >> 6);
    int lane = threadIdx.x & 63;
    if (row >= nrows) return;
    const float* p = src + (size_t)row * K_DIM + lane * 8;
    float4 a = *(const float4*)p;
    float4 b = *(const float4*)(p + 4);
    ushort8 v;
    v[0]=f2bf(a.x); v[1]=f2bf(a.y); v[2]=f2bf(a.z); v[3]=f2bf(a.w);
    v[4]=f2bf(b.x); v[5]=f2bf(b.y); v[6]=f2bf(b.z); v[7]=f2bf(b.w);
    *(ushort8*)(dst + (size_t)row * K_DIM + lane * 8) = v;
    float ss = a.x*a.x + a.y*a.y + a.z*a.z + a.w*a.w
             + b.x*b.x + b.y*b.y + b.z*b.z + b.w*b.w;
    #pragma unroll
    for (int s = 32; s; s >>= 1) ss += __shfl_xor(ss, s);
    if (lane == 0) nrm2[row] = ss;
}

// ---------------- main bf16 GEMM + fused min/candidate epilogue ----------------
// 256x256 tile, BK=64, 8 waves (2M x 4N), 8-phase pipeline, counted vmcnt.
//
// KEY (round-2 fix): ds_reads are INLINE ASM. C++ ds_reads alias the LDS
// region written by in-flight global_load_lds -> the compiler inserted a
// vmcnt(0) alias-guard drain EVERY phase (measured: MfmaUtil 17%, all pipes
// idle, ~3000 cyc/phase). Asm reads carry no memory edge; the ONLY VMEM
// waits are the hand-placed vmcnt(4) at ph4/ph8. Per guide rule #18, each
// MFMA cluster is fenced by explicit "s_waitcnt lgkmcnt(0)" + sched_barrier(0).
//
// LDS 16B-block layout per half-slab: block(row R, q) at slot (R>>3)*32+q*8+(R&7);
// staging block index b lands at LDS block b (identity) -> lane-linear dest,
// conflict-free ds_read_b128 (8 consecutive lanes = 128 contiguous bytes).
//
// Phase map (iter computes tile t=2i from buf0, u=t+1 from buf1):
//   ph1: rd B0h0,A0h0 mp0-3 | stage buf1.A.h1(u)      ph5: rd B1h0,A1h0 | stage buf0.A.h1(t+2)
//   ph2: rd A0h0 mp4-7      | stage buf1.B.h1(u)      ph6: rd A1h0 mp4-7| stage buf0.B.h1(t+2)
//   ph3: rd B0h1,A0h1 mp0-3 | stage buf0.A.h0(t+2)    ph7: rd B1h1,A1h1 | stage buf1.A.h0(t+3)
//   ph4: rd A0h1 mp4-7      | stage buf0.B.h0(t+2)    ph8: rd A1h1 mp4-7| stage buf1.B.h0(t+3)
// vmcnt(4) at ph4/ph8 retires the 8 oldest loads (all data read over the next
// 1-4 phases), leaves the newest 2 half-slabs in flight. Last iteration is
// PEELED: only ph1/ph2 stage (buf1.h1 of tile 7); VMW4@ph4, VMW0@ph6.
__global__ __launch_bounds__(512, 2)
void k_gemm(const u16* __restrict__ zb, const u16* __restrict__ eb,
            const float* __restrict__ en2, u32* __restrict__ rowMin,
            u32* __restrict__ candCnt, u64* __restrict__ cand) {
    // [buf(2)][mat A/B][khalf(2)][8192 u16] = 128 KiB
    __shared__ __align__(16) u16 lds[65536];
    __shared__ float en2s[BN];
    __shared__ u32 threshL[BM];
    __shared__ u64 candBuf[LCAP];
    __shared__ u32 ldsCnt, ldsBase;

    const int tid  = threadIdx.x;
    const int lane = tid & 63;
    const int wave = tid >> 6;          // 0..7
    const int wm   = wave >> 2;         // 0..1: row half (128 rows per wave)
    const int wn   = (wave & 3) * 64;   // col quadrant base (64 cols per wave)
    const int rowTile = blockIdx.x * BM;
    const int nTile   = blockIdx.y * BN;

    if (tid < BN) en2s[tid] = en2[nTile + tid];
    if (tid < BM) threshL[tid] = 0xFFFFFFFFu;
    if (tid == 0) ldsCnt = 0u;

    // --- staging addresses: 16B block b=(wave*2+j)*64+lane; G=b>>5,q=(b>>3)&3,r=b&7
    const u16* zbp = zb + (size_t)rowTile * K_DIM;
    const u16* ebp = eb + (size_t)nTile * K_DIM;
    int b0 = (wave*2 + 0)*64 + lane;
    int b1 = (wave*2 + 1)*64 + lane;
    const size_t gOff0 = (size_t)((b0 >> 5)*8 + (b0 & 7)) * K_DIM + ((b0 >> 3) & 3)*8;
    const size_t gOff1 = (size_t)((b1 >> 5)*8 + (b1 & 7)) * K_DIM + ((b1 >> 3) & 3)*8;
    const int lOff0 = (wave*2 + 0) * 512;
    const int lOff1 = (wave*2 + 1) * 512;

    // --- fragment read LDS byte addresses
    // slot(R,q)*16B = (R>>3)*512 + q*128 + (R&7)*16; R = M0 + (lane&15), q = lane>>4
    const int laneFB = (((lane >> 3) & 1)*256 + (lane >> 4)*64 + (lane & 7)*8) * 2;
    const u32 ldsB0 = lds_addr(lds);
    const u32 aAddr0 = ldsB0 + (u32)(wm*8192 + laneFB);          // + buf*65536 + h*16384 + mp*1024
    const u32 bAddr0 = ldsB0 + 32768u + (u32)((wave & 3)*4096 + laneFB); // + buf*65536 + h*16384

#define STAGE(buf, matB, h, tileIdx) do {                                     \
    int ko_ = (tileIdx) * BK + (h) * 32;                                      \
    const u16* g_ = (matB) ? ebp : zbp;                                       \
    u16* l_ = lds + (buf)*32768 + (matB)*16384 + (h)*8192;                    \
    ldg_to_lds16(g_ + gOff0 + ko_, l_ + lOff0);                               \
    ldg_to_lds16(g_ + gOff1 + ko_, l_ + lOff1);                               \
} while (0)

#define DSR(dst, a, IMM) asm volatile("ds_read_b128 %0, %1 offset:" #IMM      \
                                      : "=v"(dst) : "v"(a))

#define RD_A(buf, h, mpB) do {                                                \
    u32 a_ = aAddr0 + (u32)((buf)*65536 + (h)*16384 + (mpB)*1024);            \
    DSR(af[0], a_, 0);    DSR(af[1], a_, 1024);                               \
    DSR(af[2], a_, 2048); DSR(af[3], a_, 3072);                               \
} while (0)

#define RD_B(buf, h) do {                                                     \
    u32 b_ = bAddr0 + (u32)((buf)*65536 + (h)*16384);                         \
    DSR(bf[0], b_, 0);    DSR(bf[1], b_, 1024);                               \
    DSR(bf[2], b_, 2048); DSR(bf[3], b_, 3072);                               \
} while (0)

#define BARF() do { asm volatile("" ::: "memory");                            \
    __builtin_amdgcn_s_barrier(); asm volatile("" ::: "memory"); } while (0)
#define VMW4() asm volatile("s_waitcnt vmcnt(4)" ::: "memory")
#define VMW0() asm volatile("s_waitcnt vmcnt(0)" ::: "memory")
// rule #18: lgkmcnt wait + hard scheduling fence so MFMAs can't hoist above it
#define LGKM0() do { asm volatile("s_waitcnt lgkmcnt(0)" ::: "memory");       \
                     __builtin_amdgcn_sched_barrier(0); } while (0)

#define MFMA_Q(mpB) do {                                                      \
    __builtin_amdgcn_s_setprio(1);                                            \
    _Pragma("unroll") for (int m_ = 0; m_ < 4; m_++)                          \
      _Pragma("unroll") for (int n_ = 0; n_ < 4; n_++)                        \
        acc[(mpB)+m_][n_] = __builtin_amdgcn_mfma_f32_16x16x32_bf16(          \
            af[m_], bf[n_], acc[(mpB)+m_][n_], 0, 0, 0);                      \
    __builtin_amdgcn_s_setprio(0);                                            \
} while (0)

    f32x4 acc[8][4] = {};
    short8 af[4], bf[4];

    // prologue: tile0 fully + tile1 h0; vmcnt(4) -> tile0's 4 half-slabs landed
    STAGE(0,0,0,0); STAGE(0,1,0,0); STAGE(0,0,1,0); STAGE(0,1,1,0);
    STAGE(1,0,0,1); STAGE(1,1,0,1);
    VMW4();
    BARF();

    for (int i = 0; i < KTILES/2 - 1; i++) {   // iterations 0..2 (tiles 0..5)
        const int t = 2*i, u = t + 1;
        RD_B(0,0); RD_A(0,0,0); STAGE(1,0,1,u);          // ph1
        BARF(); LGKM0(); MFMA_Q(0); BARF();
        RD_A(0,0,4); STAGE(1,1,1,u);                     // ph2
        BARF(); LGKM0(); MFMA_Q(4); BARF();
        RD_B(0,1); RD_A(0,1,0); STAGE(0,0,0,t+2);        // ph3
        BARF(); LGKM0(); MFMA_Q(0); BARF();
        RD_A(0,1,4); STAGE(0,1,0,t+2); VMW4();           // ph4
        BARF(); LGKM0(); MFMA_Q(4); BARF();
        RD_B(1,0); RD_A(1,0,0); STAGE(0,0,1,t+2);        // ph5
        BARF(); LGKM0(); MFMA_Q(0); BARF();
        RD_A(1,0,4); STAGE(0,1,1,t+2);                   // ph6
        BARF(); LGKM0(); MFMA_Q(4); BARF();
        RD_B(1,1); RD_A(1,1,0); STAGE(1,0,0,t+3);        // ph7
        BARF(); LGKM0(); MFMA_Q(0); BARF();
        RD_A(1,1,4); STAGE(1,1,0,t+3); VMW4();           // ph8
        BARF(); LGKM0(); MFMA_Q(4); BARF();
    }
    {   // peeled tail: tiles 6 (buf0) and 7 (buf1); only ph1/ph2 stage.
        RD_B(0,0); RD_A(0,0,0); STAGE(1,0,1,7);          // ph1: stage buf1.A.h1(7)
        BARF(); LGKM0(); MFMA_Q(0); BARF();
        RD_A(0,0,4); STAGE(1,1,1,7);                     // ph2: stage buf1.B.h1(7)
        BARF(); LGKM0(); MFMA_Q(4); BARF();
        RD_B(0,1); RD_A(0,1,0);                          // ph3
        BARF(); LGKM0(); MFMA_Q(0); BARF();
        RD_A(0,1,4); VMW4();                             // ph4: retires buf1.h0(7)
        BARF(); LGKM0(); MFMA_Q(4); BARF();
        RD_B(1,0); RD_A(1,0,0);                          // ph5
        BARF(); LGKM0(); MFMA_Q(0); BARF();
        RD_A(1,0,4); VMW0();                             // ph6: retires buf1.h1(7)
        BARF(); LGKM0(); MFMA_Q(4); BARF();
        RD_B(1,1); RD_A(1,1,0);                          // ph7
        BARF(); LGKM0(); MFMA_Q(0); BARF();
        RD_A(1,1,4);                                     // ph8
        BARF(); LGKM0(); MFMA_Q(4); BARF();
    }

    // ---- epilogue: s = en2 - 2*C ; per-row tile min ; candidate capture ----
    // C/D layout (16x16x32): col = lane&15, row = (lane>>4)*4 + reg
    float e2v[4];
    #pragma unroll
    for (int n = 0; n < 4; n++) e2v[n] = en2s[wn + n*16 + (lane & 15)];
    #pragma unroll
    for (int m = 0; m < 8; m++)
        #pragma unroll
        for (int n = 0; n < 4; n++)
            #pragma unroll
            for (int r = 0; r < 4; r++)
                acc[m][n][r] = e2v[n] - 2.0f * acc[m][n][r];

    float rm[8][4];
    #pragma unroll
    for (int m = 0; m < 8; m++)
        #pragma unroll
        for (int r = 0; r < 4; r++)
            rm[m][r] = fminf(fminf(acc[m][0][r], acc[m][1][r]),
                             fminf(acc[m][2][r], acc[m][3][r]));
    #pragma unroll
    for (int d = 1; d < 16; d <<= 1)
        #pragma unroll
        for (int m = 0; m < 8; m++)
            #pragma unroll
            for (int r = 0; r < 4; r++)
                rm[m][r] = fminf(rm[m][r], __shfl_xor(rm[m][r], d));

    const int q4 = lane >> 4;
    if ((lane & 15) == 0) {
        #pragma unroll
        for (int m = 0; m < 8; m++)
            #pragma unroll
            for (int r = 0; r < 4; r++) {
                int lrow = wm*128 + m*16 + q4*4 + r;
                u32 o = ford(rm[m][r]);
                atomicMin(&threshL[lrow], o);
                u32 old = atomicMin(&rowMin[rowTile + lrow], o);  // tighten via earlier tiles
                atomicMin(&threshL[lrow], old);
            }
    }
    __syncthreads();

    #pragma unroll
    for (int m = 0; m < 8; m++) {
        #pragma unroll
        for (int r = 0; r < 4; r++) {
            int lrow = wm*128 + m*16 + q4*4 + r;
            float th = fordinv(threshL[lrow]) + TAU2;
            #pragma unroll
            for (int n = 0; n < 4; n++) {
                float sv = acc[m][n][r];
                if (sv <= th) {
                    u32 code = (u32)(nTile + wn + n*16 + (lane & 15));
                    u64 pk = ((u64)ford(sv) << 32) |
                             (u64)(((u32)(rowTile + lrow) << 13) | code);
                    u32 idx = atomicAdd(&ldsCnt, 1u);       // LDS atomic: cheap
                    if (idx < LCAP) candBuf[idx] = pk;
                    else { u32 g = atomicAdd(candCnt, 1u);  // rare overflow path
                           if (g < CAND_CAP) cand[g] = pk; }
                }
            }
        }
    }
    __syncthreads();
    if (tid == 0) {
        u32 n = ldsCnt < LCAP ? ldsCnt : LCAP;
        ldsBase = atomicAdd(candCnt, n);                    // ONE global atomic per block
    }
    __syncthreads();
    u32 nn = ldsCnt < LCAP ? ldsCnt : LCAP;
    for (u32 k2 = tid; k2 < nn; k2 += 512) {
        u32 g = ldsBase + k2;
        if (g < CAND_CAP) cand[g] = candBuf[k2];
    }
#undef STAGE
#undef DSR
#undef RD_A
#undef RD_B
#undef BARF
#undef VMW4
#undef VMW0
#undef LGKM0
#undef MFMA_Q
}

// ---------------- fp32 exact refine of pruned candidates ----------------
__global__ void k_refine(const float* __restrict__ z, const float* __restrict__ emb,
                         const float* __restrict__ en2, const u32* __restrict__ candCnt,
                         const u64* __restrict__ cand, const u32* __restrict__ rowMin,
                         u64* __restrict__ rowBest) {
    u32 cnt = *candCnt; if (cnt > CAND_CAP) cnt = CAND_CAP;
    int gt = blockIdx.x * blockDim.x + threadIdx.x;
    u32 wid = (u32)(gt >> 6);
    int lane = gt & 63;
    u32 nw = (u32)((gridDim.x * blockDim.x) >> 6);
    for (u32 ci = wid; ci < cnt; ci += nw) {
        u64 pk = cand[ci];
        u32 rc = (u32)pk;
        u32 row = rc >> 13, code = rc & (N_CODES - 1);
        float ad = fordinv((u32)(pk >> 32));
        float gm = fordinv(rowMin[row]);
        if (ad > gm + TAU2) continue;   // pruned: can't be the true argmin
        const float4* zp = (const float4*)(z + (size_t)row * K_DIM) + lane * 2;
        const float4* ep = (const float4*)(emb + (size_t)code * K_DIM) + lane * 2;
        float4 a0 = zp[0], a1 = zp[1], b0 = ep[0], b1 = ep[1];
        float d = a0.x*b0.x + a0.y*b0.y + a0.z*b0.z + a0.w*b0.w
                + a1.x*b1.x + a1.y*b1.y + a1.z*b1.z + a1.w*b1.w;
        #pragma unroll
        for (int s = 32; s; s >>= 1) d += __shfl_xor(d, s);
        if (lane == 0) {
            float sv = en2[code] - 2.0f * d;
            u64 bk = ((u64)ford(sv) << 32) | (u64)code;
            atomicMin(rowBest + row, bk);
        }
    }
}

// ---------------- outputs: z_q gather, codes, counts ----------------
__global__ void k_output(const u64* __restrict__ rowBest, const float* __restrict__ emb,
                         float* __restrict__ out, u32* __restrict__ counts) {
    int row = blockIdx.x;
    u64 pk = rowBest[row];
    u32 code = (u32)(pk & 0xFFFFFFFFull);
    int t = threadIdx.x;  // 128 threads, 4 floats each
    float4 v = ((const float4*)(emb + (size_t)code * K_DIM))[t];
    ((float4*)(out + (size_t)row * K_DIM))[t] = v;
    if (t == 0) {
        out[OFF_CODES + row] = (float)code;
        atomicAdd(&counts[code], 1u);
    }
}

// ---------------- loss + perplexity ----------------
__global__ void k_final(const u64* __restrict__ rowBest, const float* __restrict__ zn2,
                        const u32* __restrict__ counts, float* __restrict__ out) {
    __shared__ float red[256];
    int t = threadIdx.x;
    float s1 = 0.f;
    for (int r = t; r < M_ROWS; r += 256)
        s1 += zn2[r] + fordinv((u32)(rowBest[r] >> 32));
    red[t] = s1; __syncthreads();
    for (int w = 128; w; w >>= 1) { if (t < w) red[t] += red[t + w]; __syncthreads(); }
    float lossSum = red[0];
    __syncthreads();
    float s2 = 0.f;
    for (int c = t; c < N_CODES; c += 256) {
        float p = (float)counts[c] * (1.0f / (float)M_ROWS);
        s2 += p * logf(p + 1e-10f);
    }
    red[t] = s2; __syncthreads();
    for (int w = 128; w; w >>= 1) { if (t < w) red[t] += red[t + w]; __syncthreads(); }
    if (t == 0) {
        out[OFF_LOSS] = 0.25f * lossSum / ((float)M_ROWS * (float)K_DIM);
        out[OFF_PERP] = expf(-red[0]);
    }
}

// ---------------- workspace layout (bytes) ----------------
#define WS_ZB      ((size_t)0)                       // 32768*512*2  = 33554432
#define WS_EB      ((size_t)33554432)                // 8192*512*2   = 8388608
#define WS_EN2     ((size_t)41943040)                // 8192*4
#define WS_ZN2     ((size_t)41975808)                // 32768*4
#define WS_ROWMIN  ((size_t)42106880)                // 32768*4
#define WS_ROWBEST ((size_t)42237952)                // 32768*8
#define WS_COUNTS  ((size_t)42500096)                // 8192*4
#define WS_CANDCNT ((size_t)42532864)                // 256
#define WS_CAND    ((size_t)42533120)                // 3M*8 = 25165824 -> total ~67.7MB

extern "C" void kernel_launch(void* const* d_in, const int* in_sizes, int n_in,
                              void* d_out, int out_size, void* d_ws, size_t ws_size,
                              hipStream_t stream) {
    const float* z   = (const float*)d_in[0];
    const float* emb = (const float*)d_in[1];
    float* out = (float*)d_out;
    char* ws = (char*)d_ws;

    u16*  zb      = (u16*)(ws + WS_ZB);
    u16*  eb      = (u16*)(ws + WS_EB);
    float* en2    = (float*)(ws + WS_EN2);
    float* zn2    = (float*)(ws + WS_ZN2);
    u32*  rowMin  = (u32*)(ws + WS_ROWMIN);
    u64*  rowBest = (u64*)(ws + WS_ROWBEST);
    u32*  counts  = (u32*)(ws + WS_COUNTS);
    u32*  candCnt = (u32*)(ws + WS_CANDCNT);
    u64*  cand    = (u64*)(ws + WS_CAND);

    k_init<<<dim3(M_ROWS / 256), dim3(256), 0, stream>>>(rowMin, rowBest, counts, candCnt);
    k_convert<<<dim3(M_ROWS / 4), dim3(256), 0, stream>>>(z, zb, zn2, M_ROWS);
    k_convert<<<dim3(N_CODES / 4), dim3(256), 0, stream>>>(emb, eb, en2, N_CODES);
    k_gemm<<<dim3(M_ROWS / BM, N_CODES / BN), dim3(512), 0, stream>>>(zb, eb, en2, rowMin, candCnt, cand);
    k_refine<<<dim3(1024), dim3(256), 0, stream>>>(z, emb, en2, candCnt, cand, rowMin, rowBest);
    k_output<<<dim3(M_ROWS), dim3(128), 0, stream>>>(rowBest, emb, out, counts);
    k_final<<<dim3(1), dim3(256), 0, stream>>>(rowBest, zn2, counts, out);
}